// Round 6
// baseline (337.054 us; speedup 1.0000x reference)
//
#include <hip/hip_runtime.h>
#include <stdint.h>

// Shapes from reference
#define Bn    4
#define Cn    720
#define Hn    128
#define Wn    128
#define Pn    9
#define OFFn  80          // Cn / Pn
#define HWn   16384       // Hn * Wn (= 2^14)
#define TPB   1024        // 16 waves/block
#define NBLK  256         // persistent, 1 block/CU (128 KB LDS)
#define PLANES   (Bn * Cn)      // 2880 planes; group id = plane/80 == b*Pn+p
#define PER_XCD  (PLANES / 8)   // 360 planes per XCD
#define NSLOT    (NBLK / 8)     // 32 blocks per XCD

// ---------------------------------------------------------------------------
// Async 16B global->LDS (global_load_lds_dwordx4): per-lane GLOBAL address,
// wave-uniform LDS base, HW writes lane i at ldsbase + i*16 (linear dest).
// ---------------------------------------------------------------------------
__device__ __forceinline__ void async_ld16(const void* g, void* l)
{
    __builtin_amdgcn_global_load_lds(
        (__attribute__((address_space(1))) void*)(g),
        (__attribute__((address_space(3))) void*)(l),
        16, 0, 0);
}

// Stage one 64 KB plane: 64 segments of 1 KB (64 lanes x 16 B); wave w issues
// segments 4w..4w+3 -> 4 VMEM (vmcnt) ops per wave. Fully async.
__device__ __forceinline__ void stage_plane_async(
    const float* __restrict__ src, float* dstLDS, int tid)
{
    const int wave = tid >> 6;
    const int lane = tid & 63;
    #pragma unroll
    for (int k = 0; k < 4; ++k) {
        const int seg = wave * 4 + k;
        async_ld16(src + seg * 256 + lane * 4, dstLDS + seg * 256);
    }
}

// Per-thread gather records for a (b,p) group: 16 positions -> 48 VGPRs.
__device__ __forceinline__ void load_records(
    const float* __restrict__ loc, int gid, int tid,
    int (&rbase)[4][4], float (&rdy)[4][4], float (&rdx)[4][4])
{
    const float4* ly4 = (const float4*)(loc + (size_t)(2 * gid) * HWn);
    const float4* lx4 = ly4 + HWn / 4;
    #pragma unroll
    for (int k = 0; k < 4; ++k) {
        const int q = tid + k * TPB;
        const float4 yv = ly4[q];
        const float4 xv = lx4[q];
        #pragma unroll
        for (int j = 0; j < 4; ++j) {
            const float yq = (&yv.x)[j];
            const float xq = (&xv.x)[j];
            const float y0f = floorf(yq);
            const float x0f = floorf(xq);
            rdy[k][j] = yq - y0f;
            rdx[k][j] = xq - x0f;
            // location = uniform[0,127): strictly in-bounds; clamp is
            // defensive only (bounds the LDS address).
            const int y0 = min(max((int)y0f, 0), Hn - 2);
            const int x0 = min(max((int)x0f, 0), Wn - 2);
            rbase[k][j] = y0 * Wn + x0;
        }
    }
}

__device__ __forceinline__ void gather_channel(
    const float* __restrict__ rd, float bv, float4* __restrict__ ob4, int tid,
    const int (&rbase)[4][4], const float (&rdy)[4][4], const float (&rdx)[4][4])
{
    #pragma unroll
    for (int k = 0; k < 4; ++k) {
        const int q = tid + k * TPB;
        float4 r;
        #pragma unroll
        for (int j = 0; j < 4; ++j) {
            const float* r0 = rd + rbase[k][j];
            const float v00 = r0[0];
            const float v01 = r0[1];
            const float v10 = r0[Wn];
            const float v11 = r0[Wn + 1];
            const float dy = rdy[k][j];
            const float dx = rdx[k][j];
            const float omdy = 1.f - dy;
            const float omdx = 1.f - dx;
            (&r.x)[j] = omdy * (omdx * v00 + dx * v01)
                      + dy   * (omdx * v10 + dx * v11) + bv;
        }
        ob4[q] = r;
    }
}

// ---------------------------------------------------------------------------
// Round-5 structure with the synchronization fixed (the theory: rounds 2-5
// all plateau ~114-122 us because the per-channel __syncthreads drains
// vmcnt(0) -- waiting for output STORES and because runtime-indexed buf[cur]
// makes the prefetch may-alias the gather's ds_reads, serializing them).
//
// Fixes:
//  1) TWO named __shared__ buffers + loop unrolled x2 with compile-time
//     buffer roles -> gather(ds_read of RD) provably no-alias with the
//     in-flight prefetch (gld_lds into WR); compiler can overlap them.
//  2) Raw s_barrier with COUNTED s_waitcnt vmcnt(4) (T4): retires the 4
//     prefetch ops (oldest), lets this channel's 4 output stores stay in
//     flight across the barrier. Stores from channel i are only forced to
//     retire at channel i+1's barrier -- a full gather phase later (free).
//     Per-wave VMEM order/channel: [pf x4][(loc x8 on group entry)][st x4],
//     in-order vmcnt decrement => vmcnt(4) == "pf (and loc) retired".
//  3) __launch_bounds__(TPB,4): VGPR cap 128 (was 52) so the 48 record regs
//     + many ds_read results can be live -> more memory-level parallelism.
// ---------------------------------------------------------------------------
__global__ __launch_bounds__(TPB, 4) void dcn_persist_cnt_kernel(
    const float* __restrict__ x,
    const float* __restrict__ loc,
    const float* __restrict__ bias,
    float* __restrict__ out)
{
    __shared__ float bufA[HWn];   // 64 KB
    __shared__ float bufB[HWn];   // 64 KB

    const int g    = blockIdx.x;
    const int xcd  = g & 7;          // consecutive blocks round-robin XCDs
    const int slot = g >> 3;         // 0..31 within XCD
    const int begin = xcd * PER_XCD + (slot * PER_XCD) / NSLOT;
    const int end   = xcd * PER_XCD + ((slot + 1) * PER_XCD) / NSLOT;
    const int tid   = threadIdx.x;

    int   rbase[4][4];
    float rdy[4][4];
    float rdx[4][4];
    int prev_gid = -1;

    // Prologue: stage first plane into bufA, full drain once.
    stage_plane_async(x + (size_t)begin * HWn, bufA, tid);
    asm volatile("s_waitcnt vmcnt(0)" ::: "memory");
    __builtin_amdgcn_sched_barrier(0);
    __builtin_amdgcn_s_barrier();
    __builtin_amdgcn_sched_barrier(0);

    // One channel with static buffer roles RD (gather from) / WR (prefetch to).
#define PROCESS_CHANNEL(RD, WR)                                               \
    {                                                                         \
        if (bc + 1 < end)                                                     \
            stage_plane_async(x + (size_t)(bc + 1) * HWn, (WR), tid);         \
        __builtin_amdgcn_sched_barrier(0); /* pin pf before gather VMEM */    \
        const int gid = bc / OFFn;                                            \
        if (gid != prev_gid) {                                                \
            prev_gid = gid;                                                   \
            load_records(loc, gid, tid, rbase, rdy, rdx);                     \
        }                                                                     \
        const int   c  = bc % Cn;                                             \
        const float bv = bias[c];                                             \
        float4* ob4 = (float4*)(out + (size_t)bc * HWn);                      \
        gather_channel((RD), bv, ob4, tid, rbase, rdy, rdx);                  \
        asm volatile("s_waitcnt vmcnt(4)" ::: "memory");                      \
        __builtin_amdgcn_sched_barrier(0);                                    \
        __builtin_amdgcn_s_barrier();                                         \
        __builtin_amdgcn_sched_barrier(0);                                    \
        ++bc;                                                                 \
    }

    int bc = begin;
    while (bc < end) {
        PROCESS_CHANNEL(bufA, bufB);        // read A, prefetch into B
        if (bc >= end) break;
        PROCESS_CHANNEL(bufB, bufA);        // read B, prefetch into A
    }
#undef PROCESS_CHANNEL
}

extern "C" void kernel_launch(void* const* d_in, const int* in_sizes, int n_in,
                              void* d_out, int out_size, void* d_ws, size_t ws_size,
                              hipStream_t stream)
{
    const float* x    = (const float*)d_in[0];
    const float* loc  = (const float*)d_in[1];
    const float* bias = (const float*)d_in[2];
    float* out        = (float*)d_out;

    dim3 grid(NBLK);   // 256 persistent blocks, 1 per CU
    dcn_persist_cnt_kernel<<<grid, TPB, 0, stream>>>(x, loc, bias, out);
}